// Round 10
// baseline (240.860 us; speedup 1.0000x reference)
//
#include <hip/hip_runtime.h>

#define BB 32
#define TT 128
#define PP 512
#define DD 300
#define KT 10      // K chunks of 32 (KP = 320 = 300 data + bias slot + zeros)
#define NR 13      // retained cols per pattern (tm[13] is dead)
#define NN 6656    // P * NR (GEMM n-extent, row-major C stride)
#define AT 256     // A tiles (4096/16)
#define BT 416     // B tiles (6656/16)
#define NEG -1e30f

typedef _Float16 half8 __attribute__((ext_vector_type(8)));
typedef float floatx4 __attribute__((ext_vector_type(4)));

__device__ __forceinline__ void async_load16(const void* g, void* l) {
    __builtin_amdgcn_global_load_lds(
        (const __attribute__((address_space(1))) void*)g,
        (__attribute__((address_space(3))) void*)l, 16, 0, 0);
}

__device__ __forceinline__ floatx4 mfma16(half8 a, half8 b, floatx4 c) {
    return __builtin_amdgcn_mfma_f32_16x16x32_f16(a, b, c, 0, 0, 0);
}

// ---------------------------------------------------------------------------
// Pack into MFMA-fragment-blocked layout + error-free f16 Dekker split
// (x = hi + lo*2^-12, lo stored *4096). Chunk (tile16, kt32) = 1KB:
// half idx = lane*8+i, row = tile*16+(lane&15), k = kt*32+(lane>>4)*8+i.
// K-slot 300 carries bias (A side gets exact 1.0); slots 301..319 zero.
// ---------------------------------------------------------------------------
__global__ __launch_bounds__(256) void pack_kernel(
    const int* __restrict__ tokens, const float* __restrict__ emb,
    const float* __restrict__ diags, const float* __restrict__ bias,
    _Float16* __restrict__ AhP, _Float16* __restrict__ AlP,
    _Float16* __restrict__ BhP, _Float16* __restrict__ BlP)
{
    const int idx = blockIdx.x * 256 + threadIdx.x;
    if (idx >= (AT + BT) * KT * 64) return;
    const int chunk = idx >> 6;
    const int ln = idx & 63;

    const float* src;
    float kslot;
    _Float16 *dh, *dl;
    int kt;
    if (chunk < AT * KT) {
        const int mt = chunk / KT; kt = chunk - mt * KT;
        const int m = mt * 16 + (ln & 15);
        src = emb + (size_t)tokens[m] * DD;
        kslot = 1.0f;
        dh = AhP + (size_t)chunk * 512 + ln * 8;
        dl = AlP + (size_t)chunk * 512 + ln * 8;
    } else {
        const int c2 = chunk - AT * KT;
        const int nt = c2 / KT; kt = c2 - nt * KT;
        const int n = nt * 16 + (ln & 15);
        const int p = n / NR;
        const int srow = p * 14 + (n - p * NR);
        src = diags + (size_t)srow * DD;
        kslot = bias[srow];
        dh = BhP + (size_t)c2 * 512 + ln * 8;
        dl = BlP + (size_t)c2 * 512 + ln * 8;
    }

    const int k0 = kt * 32 + (ln >> 4) * 8;
    float v[8];
    if (k0 + 8 <= DD) {
        float4 a = *(const float4*)(src + k0);
        float4 b = *(const float4*)(src + k0 + 4);
        v[0] = a.x; v[1] = a.y; v[2] = a.z; v[3] = a.w;
        v[4] = b.x; v[5] = b.y; v[6] = b.z; v[7] = b.w;
    } else {
        #pragma unroll
        for (int i = 0; i < 8; ++i) {
            const int k = k0 + i;
            v[i] = (k < DD) ? src[k] : (k == DD ? kslot : 0.f);
        }
    }
    half8 h, l;
    #pragma unroll
    for (int i = 0; i < 8; ++i) {
        h[i] = (_Float16)v[i];
        l[i] = (_Float16)((v[i] - (float)h[i]) * 4096.f);
    }
    *(half8*)dh = h;
    *(half8*)dl = l;
}

// ---------------------------------------------------------------------------
// GEMM (R7 configuration — measured ~60 us, MfmaUtil 35%, 0 bank conflicts):
// C[m][n] = sum_k A[m][k]*B[n][k] (bias folded into k=300).
// A-fragments (hi+lo) load directly global->VGPR (frag-blocked, double-
// buffered); B (hi+lo) through LDS in exact frag layout via global_load_lds,
// double-buffered, conflict-free linear reads. 128x128 tile, 4 waves 2x2,
// 3-product f16 Dekker split, dual accumulators combined in epilogue.
// ---------------------------------------------------------------------------
__global__ __launch_bounds__(256, 2) void gemm_kernel(
    const _Float16* __restrict__ AhP, const _Float16* __restrict__ AlP,
    const _Float16* __restrict__ BhP, const _Float16* __restrict__ BlP,
    float* __restrict__ C)
{
    __shared__ __align__(16) _Float16 Bs[2][2][8][512];  // [dbuf][h/l][ntile][frag]

    const int tid = threadIdx.x;
    const int w = tid >> 6, ln = tid & 63;
    const int n0t = blockIdx.x * 8, m0t = blockIdx.y * 8;
    const int wm = w & 1, wn = w >> 1;

    floatx4 acc0[4][4], acc1[4][4];
    #pragma unroll
    for (int i = 0; i < 4; ++i)
        #pragma unroll
        for (int j = 0; j < 4; ++j) {
            acc0[i][j] = (floatx4){0.f, 0.f, 0.f, 0.f};
            acc1[i][j] = (floatx4){0.f, 0.f, 0.f, 0.f};
        }

    half8 ah[2][4], al[2][4];

    auto loadA = [&](int kt, int pb) {
        #pragma unroll
        for (int i = 0; i < 4; ++i) {
            const size_t ch = ((size_t)(m0t + wm * 4 + i) * KT + kt) * 512 + ln * 8;
            ah[pb][i] = *(const half8*)(AhP + ch);
            al[pb][i] = *(const half8*)(AlP + ch);
        }
    };
    auto stageB = [&](int kt, int buf) {
        #pragma unroll
        for (int s = 0; s < 2; ++s) {
            const int nt = w + s * 4;   // wave w stages ntiles {w, w+4}
            const size_t ch = ((size_t)(n0t + nt) * KT + kt) * 512 + ln * 8;
            async_load16(BhP + ch, &Bs[buf][0][nt][0]);
            async_load16(BlP + ch, &Bs[buf][1][nt][0]);
        }
    };

    stageB(0, 0);
    loadA(0, 0);
    __syncthreads();

    #pragma unroll
    for (int kt = 0; kt < KT; ++kt) {
        const int cb = kt & 1, nb = cb ^ 1;
        if (kt + 1 < KT) {
            loadA(kt + 1, nb);
            stageB(kt + 1, nb);
        }
        #pragma unroll
        for (int j = 0; j < 4; ++j) {
            const half8 bh = *(const half8*)&Bs[cb][0][wn * 4 + j][ln * 8];
            const half8 bl = *(const half8*)&Bs[cb][1][wn * 4 + j][ln * 8];
            #pragma unroll
            for (int i = 0; i < 4; ++i) {
                acc0[i][j] = mfma16(ah[cb][i], bh, acc0[i][j]);
                acc1[i][j] = mfma16(ah[cb][i], bl, acc1[i][j]);
                acc1[i][j] = mfma16(al[cb][i], bh, acc1[i][j]);
            }
        }
        __syncthreads();
    }

    // epilogue: C/D layout col(n)=lane&15, row(m)=(lane>>4)*4+reg
    #pragma unroll
    for (int j = 0; j < 4; ++j) {
        const int n = (n0t + wn * 4 + j) * 16 + (ln & 15);
        #pragma unroll
        for (int i = 0; i < 4; ++i) {
            const int mb = (m0t + wm * 4 + i) * 16 + (ln >> 4) * 4;
            #pragma unroll
            for (int r = 0; r < 4; ++r)
                C[(size_t)(mb + r) * NN + n] =
                    acc0[i][j][r] + acc1[i][j][r] * (1.0f / 4096.0f);
        }
    }
}

// ---------------------------------------------------------------------------
// Chunk-parallel max-sum scan (max-plus affine composition).
// FULLY UNROLLED (R7 structure) + wave-uniform 8-step sub-block skip
// (t0 >= dl -> break; dl block-uniform, chunk wave-uniform -> no divergence)
// + depth-2 register prefetch (vb[3] rotation, constant indices after
// unroll). S/s0 accumulate gated per-step on t < dl (exact).
// Block = 4 chunk-waves x 64 patterns; maps combined through 64KB LDS.
// ---------------------------------------------------------------------------
__global__ __launch_bounds__(256, 2) void scan_kernel(
    const float* __restrict__ C,
    const float* __restrict__ epsilons,
    const int* __restrict__ doc_lens,
    float* __restrict__ scores)
{
    __shared__ float smaps[64][256];   // [component][tid] = 64 KiB

    const int tid = threadIdx.x;
    const int ln = tid & 63;
    const int ch = tid >> 6;
    const int b = blockIdx.x, pg = blockIdx.y;
    const int p = pg * 64 + ln;
    const int dl = doc_lens[b];
    const bool end5 = (p < 256);

    float e[6];
    #pragma unroll
    for (int i = 0; i < 6; ++i) e[i] = epsilons[p * 6 + i];

    // map state: h_out = max(A (x) h_in, c); sc = max(S (x) h_in, s0)
    float A[7][7], c[7], S[7], s0;
    #pragma unroll
    for (int i = 0; i < 7; ++i) {
        #pragma unroll
        for (int j = 0; j < 7; ++j) A[i][j] = (i == j) ? 0.f : NEG;
        c[i] = NEG; S[i] = NEG;
    }
    s0 = NEG;

    const float* base = C + (size_t)(b * 128 + ch * 32) * NN + p * NR;

    float vb[3][NR];   // depth-2 prefetch rotation

    auto load = [&](int slot, int s) {
        const float* src = base + (size_t)s * NN;
        #pragma unroll
        for (int i = 0; i < NR; ++i) vb[slot][i] = src[i];
    };
    auto step = [&](int slot, int s) {
        const float* v = vb[slot];
        // ae stage (descending: in-place safe)
        #pragma unroll
        for (int l = 6; l >= 1; --l) {
            const float el = e[l - 1];
            #pragma unroll
            for (int j = 0; j < 7; ++j) A[l][j] = fmaxf(A[l][j], A[l - 1][j] + el);
            c[l] = fmaxf(c[l], c[l - 1] + el);
        }
        // T stage (descending: in-place safe). v[0..6]=self, v[7..12]=main
        #pragma unroll
        for (int l = 6; l >= 1; --l) {
            const float wl = v[7 + l - 1], vl = v[l];
            #pragma unroll
            for (int j = 0; j < 7; ++j)
                A[l][j] = fmaxf(A[l - 1][j] + wl, A[l][j] + vl);
            c[l] = fmaxf(c[l - 1] + wl, c[l] + vl);
        }
        #pragma unroll
        for (int j = 0; j < 7; ++j) A[0][j] += v[0];
        c[0] = fmaxf(c[0] + v[0], 0.f);
        // score accumulation, gated on t < dl (dl block-uniform)
        if (ch * 32 + s < dl) {
            #pragma unroll
            for (int j = 0; j < 7; ++j)
                S[j] = fmaxf(S[j], end5 ? A[5][j] : A[6][j]);
            s0 = fmaxf(s0, end5 ? c[5] : c[6]);
        }
    };

    load(0, 0);
    load(1, 1);
    #pragma unroll
    for (int g = 0; g < 4; ++g) {           // 8-step sub-blocks
        if (ch * 32 + g * 8 >= dl) break;   // wave-uniform skip
        #pragma unroll
        for (int s2 = 0; s2 < 8; ++s2) {
            const int s = g * 8 + s2;
            if (s + 2 < 32) load((s + 2) % 3, s + 2);
            step(s % 3, s);
        }
    }

    // publish map: components 0..48=A, 49..55=c, 56..62=S, 63=s0
    #pragma unroll
    for (int i = 0; i < 7; ++i) {
        #pragma unroll
        for (int j = 0; j < 7; ++j) smaps[i * 7 + j][tid] = A[i][j];
        smaps[49 + i][tid] = c[i];
        smaps[56 + i][tid] = S[i];
    }
    smaps[63][tid] = s0;
    __syncthreads();

    if (ch == 0) {
        float h[7];
        h[0] = 0.f;
        #pragma unroll
        for (int i = 1; i < 7; ++i) h[i] = NEG;
        float sc = NEG;
        #pragma unroll
        for (int cc = 0; cc < 4; ++cc) {
            const int src = cc * 64 + ln;
            float m = smaps[63][src];
            #pragma unroll
            for (int j = 0; j < 7; ++j) m = fmaxf(m, smaps[56 + j][src] + h[j]);
            sc = fmaxf(sc, m);
            float nh[7];
            #pragma unroll
            for (int i = 0; i < 7; ++i) {
                float x = smaps[49 + i][src];
                #pragma unroll
                for (int j = 0; j < 7; ++j)
                    x = fmaxf(x, smaps[i * 7 + j][src] + h[j]);
                nh[i] = x;
            }
            #pragma unroll
            for (int i = 0; i < 7; ++i) h[i] = nh[i];
        }
        scores[p * BB + b] = sc;
    }
}

// ---------------------------------------------------------------------------
// BatchNorm (batch stats) + sign(relu) + final linear. One block.
// ---------------------------------------------------------------------------
__global__ __launch_bounds__(512) void finalize_kernel(
    const float* __restrict__ scores,
    const float* __restrict__ bn_w,
    const float* __restrict__ bn_b,
    const float* __restrict__ fw,
    const float* __restrict__ fb,
    float* __restrict__ out)
{
    __shared__ float acc[64];
    const int p = threadIdx.x;
    if (p < 64) acc[p] = 0.f;
    __syncthreads();

    float x[32];
    const float4* sp = (const float4*)(scores + p * 32);
    #pragma unroll
    for (int i = 0; i < 8; ++i) ((float4*)x)[i] = sp[i];

    float mean = 0.f;
    #pragma unroll
    for (int i = 0; i < 32; ++i) mean += x[i];
    mean *= (1.f / 32.f);
    float var = 0.f;
    #pragma unroll
    for (int i = 0; i < 32; ++i) { const float d = x[i] - mean; var = fmaf(d, d, var); }
    var *= (1.f / 32.f);

    const float scale = (1.f / sqrtf(var + 1e-5f)) * bn_w[p];
    const float shift = bn_b[p];
    const float w0 = fw[p], w1 = fw[PP + p];

    for (int b = 0; b < 32; ++b) {
        const float v = (x[b] - mean) * scale + shift;
        const bool bin = v > 0.f;
        float v0 = bin ? w0 : 0.f;
        float v1 = bin ? w1 : 0.f;
        #pragma unroll
        for (int o = 32; o; o >>= 1) {
            v0 += __shfl_xor(v0, o);
            v1 += __shfl_xor(v1, o);
        }
        if ((threadIdx.x & 63) == 0) {
            atomicAdd(&acc[b * 2 + 0], v0);
            atomicAdd(&acc[b * 2 + 1], v1);
        }
    }
    __syncthreads();
    if (p < 64) out[p] = acc[p] + fb[p & 1];
}

// ---------------------------------------------------------------------------
extern "C" void kernel_launch(void* const* d_in, const int* in_sizes, int n_in,
                              void* d_out, int out_size, void* d_ws, size_t ws_size,
                              hipStream_t stream) {
    const int*   tokens   = (const int*)d_in[0];
    const int*   doc_lens = (const int*)d_in[1];
    const float* emb      = (const float*)d_in[2];
    const float* diags    = (const float*)d_in[3];
    const float* bias     = (const float*)d_in[4];
    const float* eps      = (const float*)d_in[5];
    const float* bnw      = (const float*)d_in[6];
    const float* bnb      = (const float*)d_in[7];
    const float* fw       = (const float*)d_in[8];
    const float* fb       = (const float*)d_in[9];
    float* out = (float*)d_out;

    float* ts     = (float*)d_ws;                    // [4096][6656] = 109 MB
    float* scores = ts + (size_t)4096 * NN;          // [512][32]
    _Float16* AhP = (_Float16*)(scores + PP * BB);   // frag-blocked packs
    _Float16* AlP = AhP + (size_t)AT * KT * 512;
    _Float16* BhP = AlP + (size_t)AT * KT * 512;
    _Float16* BlP = BhP + (size_t)BT * KT * 512;

    pack_kernel<<<(AT + BT) * KT * 64 / 256, 256, 0, stream>>>(
        tokens, emb, diags, bias, AhP, AlP, BhP, BlP);
    gemm_kernel<<<dim3(BT / 8, AT / 8), 256, 0, stream>>>(AhP, AlP, BhP, BlP, ts);
    scan_kernel<<<dim3(BB, PP / 64), 256, 0, stream>>>(ts, eps, doc_lens, scores);
    finalize_kernel<<<1, 512, 0, stream>>>(scores, bnw, bnb, fw, fb, out);
}

// Round 11
// 202.017 us; speedup vs baseline: 1.1923x; 1.1923x over previous
//
#include <hip/hip_runtime.h>

#define BB 32
#define TT 128
#define PP 512
#define DD 300
#define KT 10      // K chunks of 32 (KP = 320 = 300 data + bias slot + zeros)
#define NX 7168    // P * 14: full column set, native 14-stride scan layout
#define AT 256     // A tiles (4096/16)
#define BT 448     // B tiles (7168/16)
#define NEG -1e30f

typedef _Float16 half8 __attribute__((ext_vector_type(8)));
typedef float floatx4 __attribute__((ext_vector_type(4)));

__device__ __forceinline__ void async_load16(const void* g, void* l) {
    __builtin_amdgcn_global_load_lds(
        (const __attribute__((address_space(1))) void*)g,
        (__attribute__((address_space(3))) void*)l, 16, 0, 0);
}

__device__ __forceinline__ floatx4 mfma16(half8 a, half8 b, floatx4 c) {
    return __builtin_amdgcn_mfma_f32_16x16x32_f16(a, b, c, 0, 0, 0);
}

// ---------------------------------------------------------------------------
// Pack into MFMA-fragment-blocked layout + error-free f16 Dekker split
// (x = hi + lo*2^-12, lo stored *4096). Chunk (tile16, kt32) = 1KB:
// half idx = lane*8+i, row = tile*16+(lane&15), k = kt*32+(lane>>4)*8+i.
// B rows = diags rows 0..7167 directly (all 14 cols; col 13 output is dead
// but writing it keeps C dense 14-stride). K-slot 300 carries bias
// (A side gets exact 1.0); slots 301..319 zero.
// ---------------------------------------------------------------------------
__global__ __launch_bounds__(256) void pack_kernel(
    const int* __restrict__ tokens, const float* __restrict__ emb,
    const float* __restrict__ diags, const float* __restrict__ bias,
    _Float16* __restrict__ AhP, _Float16* __restrict__ AlP,
    _Float16* __restrict__ BhP, _Float16* __restrict__ BlP)
{
    const int idx = blockIdx.x * 256 + threadIdx.x;
    if (idx >= (AT + BT) * KT * 64) return;
    const int chunk = idx >> 6;
    const int ln = idx & 63;

    const float* src;
    float kslot;
    _Float16 *dh, *dl;
    int kt;
    if (chunk < AT * KT) {
        const int mt = chunk / KT; kt = chunk - mt * KT;
        const int m = mt * 16 + (ln & 15);
        src = emb + (size_t)tokens[m] * DD;
        kslot = 1.0f;
        dh = AhP + (size_t)chunk * 512 + ln * 8;
        dl = AlP + (size_t)chunk * 512 + ln * 8;
    } else {
        const int c2 = chunk - AT * KT;
        const int nt = c2 / KT; kt = c2 - nt * KT;
        const int n = nt * 16 + (ln & 15);       // srow = n directly
        src = diags + (size_t)n * DD;
        kslot = bias[n];
        dh = BhP + (size_t)c2 * 512 + ln * 8;
        dl = BlP + (size_t)c2 * 512 + ln * 8;
    }

    const int k0 = kt * 32 + (ln >> 4) * 8;
    float v[8];
    if (k0 + 8 <= DD) {
        float4 a = *(const float4*)(src + k0);
        float4 b = *(const float4*)(src + k0 + 4);
        v[0] = a.x; v[1] = a.y; v[2] = a.z; v[3] = a.w;
        v[4] = b.x; v[5] = b.y; v[6] = b.z; v[7] = b.w;
    } else {
        #pragma unroll
        for (int i = 0; i < 8; ++i) {
            const int k = k0 + i;
            v[i] = (k < DD) ? src[k] : (k == DD ? kslot : 0.f);
        }
    }
    half8 h, l;
    #pragma unroll
    for (int i = 0; i < 8; ++i) {
        h[i] = (_Float16)v[i];
        l[i] = (_Float16)((v[i] - (float)h[i]) * 4096.f);
    }
    *(half8*)dh = h;
    *(half8*)dl = l;
}

// ---------------------------------------------------------------------------
// GEMM (R7/R9 configuration — twice measured ~60 us; N widened to 7168):
// C[m][n] = sum_k A[m][k]*B[n][k] (bias folded into k=300).
// A-fragments (hi+lo) load directly global->VGPR (frag-blocked, double-
// buffered); B (hi+lo) through LDS in exact frag layout via global_load_lds,
// double-buffered, conflict-free linear reads. 128x128 tile, 4 waves 2x2,
// 3-product f16 Dekker split, dual accumulators combined in epilogue.
// ---------------------------------------------------------------------------
__global__ __launch_bounds__(256, 2) void gemm_kernel(
    const _Float16* __restrict__ AhP, const _Float16* __restrict__ AlP,
    const _Float16* __restrict__ BhP, const _Float16* __restrict__ BlP,
    float* __restrict__ C)
{
    __shared__ __align__(16) _Float16 Bs[2][2][8][512];  // [dbuf][h/l][ntile][frag]

    const int tid = threadIdx.x;
    const int w = tid >> 6, ln = tid & 63;
    const int n0t = blockIdx.x * 8, m0t = blockIdx.y * 8;
    const int wm = w & 1, wn = w >> 1;

    floatx4 acc0[4][4], acc1[4][4];
    #pragma unroll
    for (int i = 0; i < 4; ++i)
        #pragma unroll
        for (int j = 0; j < 4; ++j) {
            acc0[i][j] = (floatx4){0.f, 0.f, 0.f, 0.f};
            acc1[i][j] = (floatx4){0.f, 0.f, 0.f, 0.f};
        }

    half8 ah[2][4], al[2][4];

    auto loadA = [&](int kt, int pb) {
        #pragma unroll
        for (int i = 0; i < 4; ++i) {
            const size_t ch = ((size_t)(m0t + wm * 4 + i) * KT + kt) * 512 + ln * 8;
            ah[pb][i] = *(const half8*)(AhP + ch);
            al[pb][i] = *(const half8*)(AlP + ch);
        }
    };
    auto stageB = [&](int kt, int buf) {
        #pragma unroll
        for (int s = 0; s < 2; ++s) {
            const int nt = w + s * 4;   // wave w stages ntiles {w, w+4}
            const size_t ch = ((size_t)(n0t + nt) * KT + kt) * 512 + ln * 8;
            async_load16(BhP + ch, &Bs[buf][0][nt][0]);
            async_load16(BlP + ch, &Bs[buf][1][nt][0]);
        }
    };

    stageB(0, 0);
    loadA(0, 0);
    __syncthreads();

    #pragma unroll
    for (int kt = 0; kt < KT; ++kt) {
        const int cb = kt & 1, nb = cb ^ 1;
        if (kt + 1 < KT) {
            loadA(kt + 1, nb);
            stageB(kt + 1, nb);
        }
        #pragma unroll
        for (int j = 0; j < 4; ++j) {
            const half8 bh = *(const half8*)&Bs[cb][0][wn * 4 + j][ln * 8];
            const half8 bl = *(const half8*)&Bs[cb][1][wn * 4 + j][ln * 8];
            #pragma unroll
            for (int i = 0; i < 4; ++i) {
                acc0[i][j] = mfma16(ah[cb][i], bh, acc0[i][j]);
                acc1[i][j] = mfma16(ah[cb][i], bl, acc1[i][j]);
                acc1[i][j] = mfma16(al[cb][i], bh, acc1[i][j]);
            }
        }
        __syncthreads();
    }

    // epilogue: C/D layout col(n)=lane&15, row(m)=(lane>>4)*4+reg
    #pragma unroll
    for (int j = 0; j < 4; ++j) {
        const int n = (n0t + wn * 4 + j) * 16 + (ln & 15);
        #pragma unroll
        for (int i = 0; i < 4; ++i) {
            const int mb = (m0t + wm * 4 + i) * 16 + (ln >> 4) * 4;
            #pragma unroll
            for (int r = 0; r < 4; ++r)
                C[(size_t)(mb + r) * NX + n] =
                    acc0[i][j][r] + acc1[i][j][r] * (1.0f / 4096.0f);
        }
    }
}

// ---------------------------------------------------------------------------
// Max-sum scan (R2 structure — measured ~19 us — plus doc_len trip count).
// One thread per (b,p); 14-float 8B-aligned rows, 7x float2 loads, depth-4
// prefetch with STATIC slot indices (4-step unrolled body, dynamic outer
// bound tb+4 <= dl; dl is block-uniform -> no divergence). Steps beyond dl
// are provably dead (scores gated, h never queried) and are skipped.
// v[0..6]=self-loop (diag0 l0..6), v[7..12]=main (diag1 l0..5), v[13] dead.
// ---------------------------------------------------------------------------
__global__ __launch_bounds__(64) void scan_kernel(
    const float* __restrict__ ts,
    const float* __restrict__ epsilons,
    const int* __restrict__ doc_lens,
    float* __restrict__ scores)
{
    const int b = blockIdx.x;
    const int p = blockIdx.y * 64 + threadIdx.x;
    const int dl = doc_lens[b];   // in [64, 128]

    float e[6];
    #pragma unroll
    for (int i = 0; i < 6; ++i) e[i] = epsilons[p * 6 + i];

    const float* base = ts + (size_t)b * TT * NX + p * 14;

    float h0 = 0.f, h1 = NEG, h2 = NEG, h3 = NEG, h4 = NEG, h5 = NEG, h6 = NEG;
    float sc = NEG;
    const bool end5 = (p < 256);

    float2 buf[4][7];

    auto load = [&](int slot, int t) {
        const float2* s = (const float2*)(base + (size_t)t * NX);
        #pragma unroll
        for (int i = 0; i < 7; ++i) buf[slot][i] = s[i];
    };
    auto step = [&](int slot) {
        const float2* v = buf[slot];
        float ae0 = h0;
        float ae1 = fmaxf(h1, h0 + e[0]);
        float ae2 = fmaxf(h2, h1 + e[1]);
        float ae3 = fmaxf(h3, h2 + e[2]);
        float ae4 = fmaxf(h4, h3 + e[3]);
        float ae5 = fmaxf(h5, h4 + e[4]);
        float ae6 = fmaxf(h6, h5 + e[5]);
        h0 = fmaxf(0.f,            ae0 + v[0].x);
        h1 = fmaxf(ae0 + v[3].y,   ae1 + v[0].y);
        h2 = fmaxf(ae1 + v[4].x,   ae2 + v[1].x);
        h3 = fmaxf(ae2 + v[4].y,   ae3 + v[1].y);
        h4 = fmaxf(ae3 + v[5].x,   ae4 + v[2].x);
        h5 = fmaxf(ae4 + v[5].y,   ae5 + v[2].y);
        h6 = fmaxf(ae5 + v[6].x,   ae6 + v[3].x);
        sc = fmaxf(sc, end5 ? h5 : h6);   // every executed step has t < dl
    };

    #pragma unroll
    for (int j = 0; j < 4; ++j) load(j, j);

    int tb = 0;
    for (; tb + 4 <= dl; tb += 4) {
        #pragma unroll
        for (int j = 0; j < 4; ++j) {
            step(j);
            load(j, tb + j + 4);   // t <= dl+3 <= 131: stays inside d_ws
        }
    }
    const int rem = dl - tb;       // 0..3, block-uniform
    #pragma unroll
    for (int j = 0; j < 3; ++j)
        if (j < rem) step(j);

    scores[p * BB + b] = sc;
}

// ---------------------------------------------------------------------------
// BatchNorm (batch stats) + sign(relu) + final linear. One block.
// ---------------------------------------------------------------------------
__global__ __launch_bounds__(512) void finalize_kernel(
    const float* __restrict__ scores,
    const float* __restrict__ bn_w,
    const float* __restrict__ bn_b,
    const float* __restrict__ fw,
    const float* __restrict__ fb,
    float* __restrict__ out)
{
    __shared__ float acc[64];
    const int p = threadIdx.x;
    if (p < 64) acc[p] = 0.f;
    __syncthreads();

    float x[32];
    const float4* sp = (const float4*)(scores + p * 32);
    #pragma unroll
    for (int i = 0; i < 8; ++i) ((float4*)x)[i] = sp[i];

    float mean = 0.f;
    #pragma unroll
    for (int i = 0; i < 32; ++i) mean += x[i];
    mean *= (1.f / 32.f);
    float var = 0.f;
    #pragma unroll
    for (int i = 0; i < 32; ++i) { const float d = x[i] - mean; var = fmaf(d, d, var); }
    var *= (1.f / 32.f);

    const float scale = (1.f / sqrtf(var + 1e-5f)) * bn_w[p];
    const float shift = bn_b[p];
    const float w0 = fw[p], w1 = fw[PP + p];

    for (int b = 0; b < 32; ++b) {
        const float v = (x[b] - mean) * scale + shift;
        const bool bin = v > 0.f;
        float v0 = bin ? w0 : 0.f;
        float v1 = bin ? w1 : 0.f;
        #pragma unroll
        for (int o = 32; o; o >>= 1) {
            v0 += __shfl_xor(v0, o);
            v1 += __shfl_xor(v1, o);
        }
        if ((threadIdx.x & 63) == 0) {
            atomicAdd(&acc[b * 2 + 0], v0);
            atomicAdd(&acc[b * 2 + 1], v1);
        }
    }
    __syncthreads();
    if (p < 64) out[p] = acc[p] + fb[p & 1];
}

// ---------------------------------------------------------------------------
extern "C" void kernel_launch(void* const* d_in, const int* in_sizes, int n_in,
                              void* d_out, int out_size, void* d_ws, size_t ws_size,
                              hipStream_t stream) {
    const int*   tokens   = (const int*)d_in[0];
    const int*   doc_lens = (const int*)d_in[1];
    const float* emb      = (const float*)d_in[2];
    const float* diags    = (const float*)d_in[3];
    const float* bias     = (const float*)d_in[4];
    const float* eps      = (const float*)d_in[5];
    const float* bnw      = (const float*)d_in[6];
    const float* bnb      = (const float*)d_in[7];
    const float* fw       = (const float*)d_in[8];
    const float* fb       = (const float*)d_in[9];
    float* out = (float*)d_out;

    float* ts     = (float*)d_ws;                    // [4096][7168] = 117.4 MB
    float* scores = ts + (size_t)4096 * NX;          // [512][32]
    _Float16* AhP = (_Float16*)(scores + PP * BB);   // frag-blocked packs
    _Float16* AlP = AhP + (size_t)AT * KT * 512;
    _Float16* BhP = AlP + (size_t)AT * KT * 512;
    _Float16* BlP = BhP + (size_t)BT * KT * 512;

    pack_kernel<<<(AT + BT) * KT * 64 / 256, 256, 0, stream>>>(
        tokens, emb, diags, bias, AhP, AlP, BhP, BlP);
    gemm_kernel<<<dim3(BT / 8, AT / 8), 256, 0, stream>>>(AhP, AlP, BhP, BlP, ts);
    scan_kernel<<<dim3(BB, PP / 64), 64, 0, stream>>>(ts, eps, doc_lens, scores);
    finalize_kernel<<<1, 512, 0, stream>>>(scores, bnw, bnb, fw, fb, out);
}